// Round 8
// baseline (281.649 us; speedup 1.0000x reference)
//
#include <hip/hip_runtime.h>
#include <hip/hip_fp16.h>

#define HDIM 256
#define MS 16
#define LDAK 264   // 256 + 8 halves pad; 16B-group stride 33 == 1 mod 8 (b128-friendly)
#define CSTRIDE (MS * LDAK * 2)   // 8448 B per channel block

typedef _Float16 half8 __attribute__((ext_vector_type(8)));
typedef _Float16 half4 __attribute__((ext_vector_type(4)));
typedef _Float16 half2v __attribute__((ext_vector_type(2)));
typedef float f32x4 __attribute__((ext_vector_type(4)));

__device__ __forceinline__ float fast_tanh(float x) {
    // tanh(x) = 1 - 2/(e^{2x}+1); v_exp-based, graceful at +-inf
    float e = __expf(2.0f * x);
    return 1.0f - 2.0f * __builtin_amdgcn_rcpf(e + 1.0f);
}

__device__ __forceinline__ half4 cvt4(float a, float b, float c, float d) {
    half2v lo = __builtin_bit_cast(half2v, __builtin_amdgcn_cvt_pkrtz(a, b));
    half2v hi = __builtin_bit_cast(half2v, __builtin_amdgcn_cvt_pkrtz(c, d));
    half4 r; r[0] = lo[0]; r[1] = lo[1]; r[2] = hi[0]; r[3] = hi[1];
    return r;
}

// Workgroup barrier draining only LDS (lgkmcnt) — leaves in-flight global
// wf prefetches (vmcnt) pending across the barrier.
__device__ __forceinline__ void barrier_lds() {
    asm volatile("s_waitcnt lgkmcnt(0)\n\ts_barrier" ::: "memory");
}

// Pack W1,W2,W3 (fp32 [256][256]) into f16 frag layout Wp[g*8192 + frag], g = flat
// K-step l*8+s; within a step: kg-sub*2048 + n*8 + (k&7).
__global__ __launch_bounds__(256) void pack_weights(const float* __restrict__ W1,
                                                    const float* __restrict__ W2,
                                                    const float* __restrict__ W3,
                                                    _Float16* __restrict__ out) {
    int tid = blockIdx.x * 256 + threadIdx.x;  // 0..24575
    int l = tid >> 13;
    int idx = tid & 8191;   // kg*256 + n
    int kg = idx >> 8;      // k-group of 8
    int n = idx & 255;
    const float* W = (l == 0) ? W1 : (l == 1) ? W2 : W3;
    half8 v;
    #pragma unroll
    for (int j = 0; j < 8; ++j) v[j] = (_Float16)W[(kg * 8 + j) * 256 + n];
    *(half8*)(out + l * 65536 + kg * 2048 + n * 8) = v;
}

// TLP-first re-cut: 8 waves/block, N-strip 32/wave, SAME single 16-sample
// tile. Unified-RF math: acc shrinks 112->56 VGPR so the whole wave fits
// ~120 VGPR -> __launch_bounds__(512,4) = 4 waves/SIMD (2 blocks/CU, LDS
// unchanged). Per-wave MFMA duty ~25%; 4 waves fill the MFMA pipe by TLP
// instead of register-starved ILP. Keeps R7 rotation (rot=wid, 1 owned
// pre-step) + elem reg-compute/LDS-store split around barriers.
__global__ __launch_bounds__(512, 4)
void pinn_fused(const float* __restrict__ x,
                const float* __restrict__ W0,
                const float* __restrict__ b0,
                const float* __restrict__ b1,
                const float* __restrict__ b2,
                const float* __restrict__ b3,
                const float* __restrict__ Wout,
                const float* __restrict__ bout,
                const _Float16* __restrict__ Wp,
                float* __restrict__ out) {
    // A: stacked [7 channels x 16 samples] rows x 256 k, f16, pad-264
    __shared__ __align__(16) _Float16 Abuf[7 * MS][LDAK];
    __shared__ float part[8 * 7 * MS];   // per-wave output partials (3584 B)

    const int tid  = threadIdx.x;
    const int lane = tid & 63;
    const int wid  = tid >> 6;        // wave 0..7 -> n-strip base wid*32
    const int qd   = lane >> 4;
    const int n15  = lane & 15;
    const int base = blockIdx.x * MS;
    const int nw   = wid * 32 + n15;
    const int rot  = wid;             // wave-owned k-step rotation (1 step)

    // Linear W addressing: frag(g,t) at Wbase + g*8192 + t*128 (halves).
    const _Float16* Wbase = Wp + (qd * 256 + nw) * 8;

    const char* Ab = (const char*)Abuf;
    const int abase = (n15 * LDAK + qd * 8) * 2;                 // read base (bytes)
    char* Sb = (char*)Abuf;
    const int sbase = (n15 * LDAK + wid * 32 + qd * 4) * 2;      // write base (bytes)

    // 2-deep ping-pong W-fragment pipeline; 2 n-frags per step (32-col strip).
    half8 wf[2][2];

#define PREFJ(JJ) do { \
    if ((JJ) < 24) { \
        const int g_ = (((JJ) >> 3) * 8 + ((rot + ((JJ) & 7)) & 7)); \
        _Pragma("unroll") \
        for (int t_ = 0; t_ < 2; ++t_) \
            wf[(JJ) & 1][t_] = *(const half8*)(Wbase + g_ * 8192 + t_ * 128); \
    } \
} while (0)

// Load the 7 per-channel A fragments of rotated position I into AF.
#define LDAFS(AF, I) do { \
    const int so_ = ((rot + (I)) & 7) * 64; \
    _Pragma("unroll") \
    for (int c_ = 0; c_ < 7; ++c_) \
        AF[c_] = *(const half8*)(Ab + abase + c_ * CSTRIDE + so_); \
} while (0)

// 14 MFMAs at position JJ consuming AF; prefetch wf for JJ+1.
#define MMSJ(ACC, AF, JJ) do { \
    PREFJ((JJ) + 1); \
    __builtin_amdgcn_s_setprio(1); \
    _Pragma("unroll") \
    for (int c_ = 0; c_ < 7; ++c_) \
        _Pragma("unroll") \
        for (int t_ = 0; t_ < 2; ++t_) \
            ACC[c_][t_] = __builtin_amdgcn_mfma_f32_16x16x32_f16(wf[(JJ) & 1][t_], AF[c_], ACC[c_][t_], 0, 0, 0); \
    __builtin_amdgcn_s_setprio(0); \
} while (0)

// PRE: position 0 of layer L = step wid, reading ONLY this wave's own
// freshly-written 32-col region -> legal before the layer barrier.
#define KPRE(ACC, L) do { \
    half8 af_[7]; \
    LDAFS(af_, 0); \
    MMSJ(ACC, af_, (L) * 8 + 0); \
} while (0)

// POST: positions 1..7 (other waves' regions) after the barrier; af
// load-use (single buffer) — latency hidden by 4-wave TLP, not regs.
#define KPOST(ACC, L) do { \
    half8 af_[7]; \
    LDAFS(af_, 1); MMSJ(ACC, af_, (L) * 8 + 1); \
    LDAFS(af_, 2); MMSJ(ACC, af_, (L) * 8 + 2); \
    LDAFS(af_, 3); MMSJ(ACC, af_, (L) * 8 + 3); \
    LDAFS(af_, 4); MMSJ(ACC, af_, (L) * 8 + 4); \
    LDAFS(af_, 5); MMSJ(ACC, af_, (L) * 8 + 5); \
    LDAFS(af_, 6); MMSJ(ACC, af_, (L) * 8 + 6); \
    LDAFS(af_, 7); MMSJ(ACC, af_, (L) * 8 + 7); \
} while (0)

#define ZACC(A_) do { \
    _Pragma("unroll") \
    for (int c_ = 0; c_ < 7; ++c_) \
        _Pragma("unroll") \
        for (int t_ = 0; t_ < 2; ++t_) A_[c_][t_] = (f32x4){0.f, 0.f, 0.f, 0.f}; \
} while (0)

// elem compute (REGISTERS ONLY — runs before the post-K barrier):
// lane holds Z[m = n15][n = wid*32 + tt*16 + qd*4 + r], r=0..3
#define ELEMC(ACC, BB, EV) do { \
    _Pragma("unroll") \
    for (int tt_ = 0; tt_ < 2; ++tt_) { \
        const int ncol_ = wid * 32 + tt_ * 16 + qd * 4; \
        f32x4 bv_ = *(const f32x4*)((BB) + ncol_); \
        float tv_[4], gj_[3][4], sj_[3][4]; \
        _Pragma("unroll") \
        for (int r_ = 0; r_ < 4; ++r_) { \
            float zv_ = ACC[0][tt_][r_] + bv_[r_]; \
            tv_[r_] = fast_tanh(zv_); \
            float dd_ = 1.f - tv_[r_] * tv_[r_]; \
            float c2_ = -2.f * tv_[r_] * dd_; \
            _Pragma("unroll") \
            for (int i_ = 0; i_ < 3; ++i_) { \
                float zg_ = ACC[1 + i_][tt_][r_]; \
                float zs_ = ACC[4 + i_][tt_][r_]; \
                gj_[i_][r_] = dd_ * zg_; \
                sj_[i_][r_] = dd_ * zs_ + c2_ * zg_ * zg_; \
            } \
        } \
        EV[0][tt_] = cvt4(tv_[0], tv_[1], tv_[2], tv_[3]); \
        _Pragma("unroll") \
        for (int i_ = 0; i_ < 3; ++i_) { \
            EV[1 + i_][tt_] = cvt4(gj_[i_][0], gj_[i_][1], gj_[i_][2], gj_[i_][3]); \
            EV[4 + i_][tt_] = cvt4(sj_[i_][0], sj_[i_][1], sj_[i_][2], sj_[i_][3]); \
        } \
    } \
} while (0)

// elem store (after the barrier; 14 cheap ds_writes to this wave's region)
#define ELEMS(EV) do { \
    _Pragma("unroll") \
    for (int c_ = 0; c_ < 7; ++c_) \
        _Pragma("unroll") \
        for (int tt_ = 0; tt_ < 2; ++tt_) \
            *(half4*)(Sb + sbase + c_ * CSTRIDE + tt_ * 32) = EV[c_][tt_]; \
} while (0)

    f32x4 acc[7][2];
    half4 ev[7][2];

    ZACC(acc);
    PREFJ(0);

    // ---------------- layer 0: 3 -> 256, jets analytic; writes OWN region ----------------
    {
        const int m  = tid & 15;
        const int n0 = (tid >> 4) * 8;    // 512 threads x 8-col chunk = 256 cols x16 samples
        const float x0 = x[(base + m) * 3 + 0];
        const float x1 = x[(base + m) * 3 + 1];
        const float x2 = x[(base + m) * 3 + 2];
        f32x4 w0v[2], w1v[2], w2v[2], bv[2];
        w0v[0] = *(const f32x4*)(W0 + n0);            w0v[1] = *(const f32x4*)(W0 + n0 + 4);
        w1v[0] = *(const f32x4*)(W0 + HDIM + n0);     w1v[1] = *(const f32x4*)(W0 + HDIM + n0 + 4);
        w2v[0] = *(const f32x4*)(W0 + 2 * HDIM + n0); w2v[1] = *(const f32x4*)(W0 + 2 * HDIM + n0 + 4);
        bv[0]  = *(const f32x4*)(b0 + n0);            bv[1]  = *(const f32x4*)(b0 + n0 + 4);
        half8 h[7];
        #pragma unroll
        for (int r = 0; r < 8; ++r) {
            const float w0 = w0v[r >> 2][r & 3];
            const float w1 = w1v[r >> 2][r & 3];
            const float w2 = w2v[r >> 2][r & 3];
            float z  = x0 * w0 + x1 * w1 + x2 * w2 + bv[r >> 2][r & 3];
            float tv = fast_tanh(z);
            float dd = 1.f - tv * tv;
            float c2 = -2.f * tv * dd;
            h[0][r] = (_Float16)tv;
            h[1][r] = (_Float16)(dd * w0);
            h[2][r] = (_Float16)(dd * w1);
            h[3][r] = (_Float16)(dd * w2);
            h[4][r] = (_Float16)(c2 * w0 * w0);
            h[5][r] = (_Float16)(c2 * w1 * w1);
            h[6][r] = (_Float16)(c2 * w2 * w2);
        }
        #pragma unroll
        for (int c = 0; c < 7; ++c)
            *(half8*)&Abuf[c * MS + m][n0] = h[c];
    }
    // K1 pre-step on own region (no barrier yet; same-wave LDS pipe ordering)
    KPRE(acc, 0);
    barrier_lds();          // B2(0)

    // ---------------- layer 1 ----------------
    KPOST(acc, 0);
    ELEMC(acc, b1, ev);     // register-only; pads B1(1)
    barrier_lds();          // B1(1): all waves done reading layer-1 Abuf
    ELEMS(ev);
    ZACC(acc);
    KPRE(acc, 1);           // own-region step of layer 2; pads B2(1)
    barrier_lds();          // B2(1)

    // ---------------- layer 2 ----------------
    KPOST(acc, 1);
    ELEMC(acc, b2, ev);
    barrier_lds();          // B1(2)
    ELEMS(ev);
    ZACC(acc);
    KPRE(acc, 2);
    barrier_lds();          // B2(2)

    // ---------------- layer 3: K POST + FUSED output ----------------
    KPOST(acc, 2);
    {
        // per-lane partial dot with Wout over this lane's 8 columns (fp32 path)
        float p[7] = {0.f, 0.f, 0.f, 0.f, 0.f, 0.f, 0.f};
        #pragma unroll
        for (int t = 0; t < 2; ++t) {
            const int ncol = wid * 32 + t * 16 + qd * 4;
            f32x4 bv = *(const f32x4*)(b3 + ncol);
            f32x4 wv = *(const f32x4*)(Wout + ncol);
            #pragma unroll
            for (int r = 0; r < 4; ++r) {
                float zv = acc[0][t][r] + bv[r];
                float tv = fast_tanh(zv);
                float dd = 1.f - tv * tv;
                float c2 = -2.f * tv * dd;
                p[0] += tv * wv[r];
                #pragma unroll
                for (int i = 0; i < 3; ++i) {
                    float zg = acc[1 + i][t][r];
                    float zs = acc[4 + i][t][r];
                    p[1 + i] += (dd * zg) * wv[r];
                    p[4 + i] += (dd * zs + c2 * zg * zg) * wv[r];
                }
            }
        }
        // reduce over the 4 qd lanes sharing sample n15
        #pragma unroll
        for (int c = 0; c < 7; ++c) {
            p[c] += __shfl_xor(p[c], 16, 64);
            p[c] += __shfl_xor(p[c], 32, 64);
        }
        if (lane < 16) {
            #pragma unroll
            for (int c = 0; c < 7; ++c)
                part[(wid * 7 + c) * MS + lane] = p[c];
        }
    }
    barrier_lds();

    // ---------------- final reduce across the 8 waves; store [B,7] ----------------
    if (tid < 7 * MS) {
        const int c = tid >> 4;   // channel
        const int m = tid & 15;   // sample
        float v = 0.f;
        #pragma unroll
        for (int w = 0; w < 8; ++w) v += part[(w * 7 + c) * MS + m];
        if (c == 0) v += bout[0];
        out[(base + m) * 7 + c] = v;
    }

#undef PREFJ
#undef LDAFS
#undef MMSJ
#undef KPRE
#undef KPOST
#undef ZACC
#undef ELEMC
#undef ELEMS
}

extern "C" void kernel_launch(void* const* d_in, const int* in_sizes, int n_in,
                              void* d_out, int out_size, void* d_ws, size_t ws_size,
                              hipStream_t stream) {
    const float* xp   = (const float*)d_in[0];
    const float* W0   = (const float*)d_in[1];
    const float* b0   = (const float*)d_in[2];
    const float* W1   = (const float*)d_in[3];
    const float* b1   = (const float*)d_in[4];
    const float* W2   = (const float*)d_in[5];
    const float* b2   = (const float*)d_in[6];
    const float* W3   = (const float*)d_in[7];
    const float* b3   = (const float*)d_in[8];
    const float* Wout = (const float*)d_in[9];
    const float* bout = (const float*)d_in[10];
    _Float16* Wp = (_Float16*)d_ws;  // 3 * 65536 halves = 384 KB

    pack_weights<<<96, 256, 0, stream>>>(W1, W2, W3, Wp);
    pinn_fused<<<65536 / MS, 512, 0, stream>>>(xp, W0, b0, b1, b2, b3, Wout, bout, Wp,
                                               (float*)d_out);
}

// Round 9
// 249.336 us; speedup vs baseline: 1.1296x; 1.1296x over previous
//
#include <hip/hip_runtime.h>
#include <hip/hip_fp16.h>

#define HDIM 256
#define MS 16
#define LDAK 264   // 256 + 8 halves pad; 16B-group stride 33 (odd) spreads banks
#define CSTRIDE (MS * LDAK * 2)   // 8448 B per channel block

typedef _Float16 half8 __attribute__((ext_vector_type(8)));
typedef _Float16 half4 __attribute__((ext_vector_type(4)));
typedef _Float16 half2v __attribute__((ext_vector_type(2)));
typedef float f32x4 __attribute__((ext_vector_type(4)));

__device__ __forceinline__ float fast_tanh(float x) {
    // tanh(x) = 1 - 2/(e^{2x}+1); v_exp-based, graceful at +-inf
    float e = __expf(2.0f * x);
    return 1.0f - 2.0f * __builtin_amdgcn_rcpf(e + 1.0f);
}

__device__ __forceinline__ half4 cvt4(float a, float b, float c, float d) {
    half2v lo = __builtin_bit_cast(half2v, __builtin_amdgcn_cvt_pkrtz(a, b));
    half2v hi = __builtin_bit_cast(half2v, __builtin_amdgcn_cvt_pkrtz(c, d));
    half4 r; r[0] = lo[0]; r[1] = lo[1]; r[2] = hi[0]; r[3] = hi[1];
    return r;
}

// Workgroup barrier draining only LDS (lgkmcnt) — leaves in-flight global
// wf loads (vmcnt) pending across the barrier.
__device__ __forceinline__ void barrier_lds() {
    asm volatile("s_waitcnt lgkmcnt(0)\n\ts_barrier" ::: "memory");
}

// Pack W1,W2,W3 (fp32 [256][256]) into f16 frag layout Wp[g*8192 + frag], g = flat
// K-step l*8+s; within a step: kg-sub*2048 + n*8 + (k&7).
__global__ __launch_bounds__(256) void pack_weights(const float* __restrict__ W1,
                                                    const float* __restrict__ W2,
                                                    const float* __restrict__ W3,
                                                    _Float16* __restrict__ out) {
    int tid = blockIdx.x * 256 + threadIdx.x;  // 0..24575
    int l = tid >> 13;
    int idx = tid & 8191;   // kg*256 + n
    int kg = idx >> 8;      // k-group of 8
    int n = idx & 255;
    const float* W = (l == 0) ? W1 : (l == 1) ? W2 : W3;
    half8 v;
    #pragma unroll
    for (int j = 0; j < 8; ++j) v[j] = (_Float16)W[(kg * 8 + j) * 256 + n];
    *(half8*)(out + l * 65536 + kg * 2048 + n * 8) = v;
}

// Register-lean TLP re-cut of R8: 8 waves/block, N-strip 32, 4 waves/SIMD.
// R8's spill (VGPR budget 128/wave, demand ~145 -> 400 MB scratch traffic)
// is fixed by: single-buffer wf (8 regs, reloaded per step; L2 latency is
// covered by 4-wave TLP), and fused elem compute+store after the barrier
// (no ev buffer). Peak demand ~105-110 regs incl. the 56-reg acc.
__global__ __launch_bounds__(512, 4)
void pinn_fused(const float* __restrict__ x,
                const float* __restrict__ W0,
                const float* __restrict__ b0,
                const float* __restrict__ b1,
                const float* __restrict__ b2,
                const float* __restrict__ b3,
                const float* __restrict__ Wout,
                const float* __restrict__ bout,
                const _Float16* __restrict__ Wp,
                float* __restrict__ out) {
    // A: stacked [7 channels x 16 samples] rows x 256 k, f16, pad-264
    __shared__ __align__(16) _Float16 Abuf[7 * MS][LDAK];
    __shared__ float part[8 * 7 * MS];   // per-wave output partials (3584 B)

    const int tid  = threadIdx.x;
    const int lane = tid & 63;
    const int wid  = tid >> 6;        // wave 0..7 -> n-strip base wid*32
    const int qd   = lane >> 4;
    const int n15  = lane & 15;
    const int base = blockIdx.x * MS;
    const int nw   = wid * 32 + n15;
    const int rot  = wid;             // wave k-step rotation: de-convoys waves

    // Linear W addressing: frag(g,t) at Wbase + g*8192 + t*128 (halves).
    const _Float16* Wbase = Wp + (qd * 256 + nw) * 8;

    const char* Ab = (const char*)Abuf;
    const int abase = (n15 * LDAK + qd * 8) * 2;                 // read base (bytes)
    char* Sb = (char*)Abuf;
    const int sbase = (n15 * LDAK + wid * 32 + qd * 4) * 2;      // write base (bytes)

// One K-step at rotated position I of layer L: load W frags (single
// buffer, from L2), load 7 A frags from LDS, issue 14 MFMAs. Load-to-use
// latency is hidden by 4-wave TLP, not by register pipelining.
#define KSTEP(ACC, L, I) do { \
    const int s_ = (rot + (I)) & 7; \
    const int g_ = (L) * 8 + s_; \
    half8 wf_[2]; \
    wf_[0] = *(const half8*)(Wbase + g_ * 8192); \
    wf_[1] = *(const half8*)(Wbase + g_ * 8192 + 128); \
    half8 af_[7]; \
    _Pragma("unroll") \
    for (int c_ = 0; c_ < 7; ++c_) \
        af_[c_] = *(const half8*)(Ab + abase + c_ * CSTRIDE + s_ * 64); \
    __builtin_amdgcn_s_setprio(1); \
    _Pragma("unroll") \
    for (int c_ = 0; c_ < 7; ++c_) \
        _Pragma("unroll") \
        for (int t_ = 0; t_ < 2; ++t_) \
            ACC[c_][t_] = __builtin_amdgcn_mfma_f32_16x16x32_f16(wf_[t_], af_[c_], ACC[c_][t_], 0, 0, 0); \
    __builtin_amdgcn_s_setprio(0); \
} while (0)

// PRE: position 0 = step wid, reading ONLY this wave's own freshly-written
// 32-col region -> legal before the layer barrier (same-wave LDS ordering).
#define KPRE(ACC, L) KSTEP(ACC, L, 0)

#define KPOST(ACC, L) do { \
    KSTEP(ACC, L, 1); KSTEP(ACC, L, 2); KSTEP(ACC, L, 3); KSTEP(ACC, L, 4); \
    KSTEP(ACC, L, 5); KSTEP(ACC, L, 6); KSTEP(ACC, L, 7); \
} while (0)

#define ZACC(A_) do { \
    _Pragma("unroll") \
    for (int c_ = 0; c_ < 7; ++c_) \
        _Pragma("unroll") \
        for (int t_ = 0; t_ < 2; ++t_) A_[c_][t_] = (f32x4){0.f, 0.f, 0.f, 0.f}; \
} while (0)

// elem: fused compute + LDS store (runs after the B1 barrier).
// lane holds Z[m = n15][n = wid*32 + tt*16 + qd*4 + r], r=0..3
#define ELEM(ACC, BB) do { \
    _Pragma("unroll") \
    for (int tt_ = 0; tt_ < 2; ++tt_) { \
        const int ncol_ = wid * 32 + tt_ * 16 + qd * 4; \
        f32x4 bv_ = *(const f32x4*)((BB) + ncol_); \
        float tv_[4], gj_[3][4], sj_[3][4]; \
        _Pragma("unroll") \
        for (int r_ = 0; r_ < 4; ++r_) { \
            float zv_ = ACC[0][tt_][r_] + bv_[r_]; \
            tv_[r_] = fast_tanh(zv_); \
            float dd_ = 1.f - tv_[r_] * tv_[r_]; \
            float c2_ = -2.f * tv_[r_] * dd_; \
            _Pragma("unroll") \
            for (int i_ = 0; i_ < 3; ++i_) { \
                float zg_ = ACC[1 + i_][tt_][r_]; \
                float zs_ = ACC[4 + i_][tt_][r_]; \
                gj_[i_][r_] = dd_ * zg_; \
                sj_[i_][r_] = dd_ * zs_ + c2_ * zg_ * zg_; \
            } \
        } \
        *(half4*)(Sb + sbase + 0 * CSTRIDE + tt_ * 32) = cvt4(tv_[0], tv_[1], tv_[2], tv_[3]); \
        _Pragma("unroll") \
        for (int i_ = 0; i_ < 3; ++i_) { \
            *(half4*)(Sb + sbase + (1 + i_) * CSTRIDE + tt_ * 32) = \
                cvt4(gj_[i_][0], gj_[i_][1], gj_[i_][2], gj_[i_][3]); \
            *(half4*)(Sb + sbase + (4 + i_) * CSTRIDE + tt_ * 32) = \
                cvt4(sj_[i_][0], sj_[i_][1], sj_[i_][2], sj_[i_][3]); \
        } \
    } \
} while (0)

    f32x4 acc[7][2];
    ZACC(acc);

    // ---------------- layer 0: 3 -> 256, jets analytic; one 8-col chunk/thread ----------------
    {
        const int m  = tid & 15;
        const int n0 = (tid >> 4) * 8;    // 512 threads x 8 cols = 256 cols x 16 samples
        const float x0 = x[(base + m) * 3 + 0];
        const float x1 = x[(base + m) * 3 + 1];
        const float x2 = x[(base + m) * 3 + 2];
        f32x4 w0v[2], w1v[2], w2v[2], bv[2];
        w0v[0] = *(const f32x4*)(W0 + n0);            w0v[1] = *(const f32x4*)(W0 + n0 + 4);
        w1v[0] = *(const f32x4*)(W0 + HDIM + n0);     w1v[1] = *(const f32x4*)(W0 + HDIM + n0 + 4);
        w2v[0] = *(const f32x4*)(W0 + 2 * HDIM + n0); w2v[1] = *(const f32x4*)(W0 + 2 * HDIM + n0 + 4);
        bv[0]  = *(const f32x4*)(b0 + n0);            bv[1]  = *(const f32x4*)(b0 + n0 + 4);
        half8 h[7];
        #pragma unroll
        for (int r = 0; r < 8; ++r) {
            const float w0 = w0v[r >> 2][r & 3];
            const float w1 = w1v[r >> 2][r & 3];
            const float w2 = w2v[r >> 2][r & 3];
            float z  = x0 * w0 + x1 * w1 + x2 * w2 + bv[r >> 2][r & 3];
            float tv = fast_tanh(z);
            float dd = 1.f - tv * tv;
            float c2 = -2.f * tv * dd;
            h[0][r] = (_Float16)tv;
            h[1][r] = (_Float16)(dd * w0);
            h[2][r] = (_Float16)(dd * w1);
            h[3][r] = (_Float16)(dd * w2);
            h[4][r] = (_Float16)(c2 * w0 * w0);
            h[5][r] = (_Float16)(c2 * w1 * w1);
            h[6][r] = (_Float16)(c2 * w2 * w2);
        }
        #pragma unroll
        for (int c = 0; c < 7; ++c)
            *(half8*)&Abuf[c * MS + m][n0] = h[c];
    }
    // Own-region K1 pre-step (wave w's threads wrote cols [64*(wid/2)...];
    // NOTE: layer-0 col ownership here is by (tid>>4), which for wave w
    // covers cols [wid*64 .. wid*64+64) of HALF the samples — NOT the full
    // own-region guarantee. So for layer 0 we must barrier BEFORE KPRE.
    barrier_lds();          // B0: layer-0 jets visible
    KPRE(acc, 0);

    // ---------------- layer 1 ----------------
    KPOST(acc, 0);
    barrier_lds();          // B1(1): all waves done reading layer-1 Abuf
    ELEM(acc, b1);
    ZACC(acc);
    KPRE(acc, 1);           // own-region step of layer 2; pads B2(1)
    barrier_lds();          // B2(1)

    // ---------------- layer 2 ----------------
    KPOST(acc, 1);
    barrier_lds();          // B1(2)
    ELEM(acc, b2);
    ZACC(acc);
    KPRE(acc, 2);
    barrier_lds();          // B2(2)

    // ---------------- layer 3: K POST + FUSED output ----------------
    KPOST(acc, 2);
    {
        // per-lane partial dot with Wout over this lane's 8 columns (fp32 path)
        float p[7] = {0.f, 0.f, 0.f, 0.f, 0.f, 0.f, 0.f};
        #pragma unroll
        for (int t = 0; t < 2; ++t) {
            const int ncol = wid * 32 + t * 16 + qd * 4;
            f32x4 bv = *(const f32x4*)(b3 + ncol);
            f32x4 wv = *(const f32x4*)(Wout + ncol);
            #pragma unroll
            for (int r = 0; r < 4; ++r) {
                float zv = acc[0][t][r] + bv[r];
                float tv = fast_tanh(zv);
                float dd = 1.f - tv * tv;
                float c2 = -2.f * tv * dd;
                p[0] += tv * wv[r];
                #pragma unroll
                for (int i = 0; i < 3; ++i) {
                    float zg = acc[1 + i][t][r];
                    float zs = acc[4 + i][t][r];
                    p[1 + i] += (dd * zg) * wv[r];
                    p[4 + i] += (dd * zs + c2 * zg * zg) * wv[r];
                }
            }
        }
        // reduce over the 4 qd lanes sharing sample n15
        #pragma unroll
        for (int c = 0; c < 7; ++c) {
            p[c] += __shfl_xor(p[c], 16, 64);
            p[c] += __shfl_xor(p[c], 32, 64);
        }
        if (lane < 16) {
            #pragma unroll
            for (int c = 0; c < 7; ++c)
                part[(wid * 7 + c) * MS + lane] = p[c];
        }
    }
    barrier_lds();

    // ---------------- final reduce across the 8 waves; store [B,7] ----------------
    if (tid < 7 * MS) {
        const int c = tid >> 4;   // channel
        const int m = tid & 15;   // sample
        float v = 0.f;
        #pragma unroll
        for (int w = 0; w < 8; ++w) v += part[(w * 7 + c) * MS + m];
        if (c == 0) v += bout[0];
        out[(base + m) * 7 + c] = v;
    }

#undef KSTEP
#undef KPRE
#undef KPOST
#undef ZACC
#undef ELEM
}

extern "C" void kernel_launch(void* const* d_in, const int* in_sizes, int n_in,
                              void* d_out, int out_size, void* d_ws, size_t ws_size,
                              hipStream_t stream) {
    const float* xp   = (const float*)d_in[0];
    const float* W0   = (const float*)d_in[1];
    const float* b0   = (const float*)d_in[2];
    const float* W1   = (const float*)d_in[3];
    const float* b1   = (const float*)d_in[4];
    const float* W2   = (const float*)d_in[5];
    const float* b2   = (const float*)d_in[6];
    const float* W3   = (const float*)d_in[7];
    const float* b3   = (const float*)d_in[8];
    const float* Wout = (const float*)d_in[9];
    const float* bout = (const float*)d_in[10];
    _Float16* Wp = (_Float16*)d_ws;  // 3 * 65536 halves = 384 KB

    pack_weights<<<96, 256, 0, stream>>>(W1, W2, W3, Wp);
    pinn_fused<<<65536 / MS, 512, 0, stream>>>(xp, W0, b0, b1, b2, b3, Wout, bout, Wp,
                                               (float*)d_out);
}